// Round 3
// baseline (123.787 us; speedup 1.0000x reference)
//
#include <hip/hip_runtime.h>
#include <hip/hip_bf16.h>

#define INNER 31999
#define VOCAB 32000
#define DEPTH 18
#define M_DIM 64      // B*T = 4*16
#define K_DIM 512     // D
#define LDS_K (K_DIM + 8)   // +8 bf16 pad -> 2-way-max (free) ds_read_b128

// Byte offset of the Lm table relative to Lp within the workspace.
#define LM_BYTE_OFF 4194304u
#define LOG_EPS -20.723265f   // log(1e-9): reference's per-depth clip floor

typedef __attribute__((ext_vector_type(8))) short bf16x8;
typedef __attribute__((ext_vector_type(4))) short s16x4;
typedef __attribute__((ext_vector_type(4))) float f32x4;
typedef __attribute__((ext_vector_type(2))) _Float16 f16x2;

// Pack two fp32 -> bf16x2 in one dword (round-half-up + v_perm).
__device__ __forceinline__ unsigned int pkbf(float a, float b) {
    const unsigned int ua = __float_as_uint(a) + 0x8000u;
    const unsigned int ub = __float_as_uint(b) + 0x8000u;
    return __builtin_amdgcn_perm(ub, ua, 0x07060302u);  // [a.hi16 | b.hi16]
}

__device__ __forceinline__ bf16x8 cvt8(f32x4 lo, f32x4 hi) {
    union { unsigned int u[4]; bf16x8 v; } r;
    r.u[0] = pkbf(lo[0], lo[1]);
    r.u[1] = pkbf(lo[2], lo[3]);
    r.u[2] = pkbf(hi[0], hi[1]);
    r.u[3] = pkbf(hi[2], hi[3]);
    return r.v;
}

// Kernel 1: x[n][m] = sum_k W[n][k]*att[m][k] (bf16 MFMA, fp32 accum), then
// epilogue computes both log-sigmoids once per (n,m) and stores f16 tables
// Lp/Lm (18x fewer transcendental evals than doing it in kernel 2).
// R10 change: W loads are NON-TEMPORAL — each W line is read exactly once
// device-wide, so caching it in L2 only evicts data with real reuse (att,
// and the Lp/Lm lines kernel 2 will gather). R9's explicit 2-deep pipeline
// was null (compiler already schedules loads under full unroll) but is
// harmless; kept.
__global__ __launch_bounds__(256) void gemm_ls_kernel(
    const float* __restrict__ W,     // [31999][512] fp32
    const float* __restrict__ att,   // [64][512] fp32
    _Float16* __restrict__ Lp,       // [32000][64] f16: logsig(+x)
    _Float16* __restrict__ Lm)       // [32000][64] f16: logsig(-x)
{
    __shared__ __align__(16) unsigned short attb[M_DIM * LDS_K];  // 65 KB bf16

    const int tid  = threadIdx.x;
    const int wave = tid >> 6;
    const int lane = tid & 63;
    const int mrow = lane & 15;
    const int quad = lane >> 4;
    const int q8   = quad * 8;

    // Stage att (128 KB fp32, L2-resident) -> LDS bf16, coalesced, once.
    #pragma unroll
    for (int i = 0; i < 32; i++) {
        const int f4 = i * 256 + tid;            // float4 index, 0..8191
        const f32x4 v = ((const f32x4*)att)[f4];
        const int f = f4 * 4;
        const int m = f >> 9, k = f & (K_DIM - 1);
        union { unsigned int u[2]; s16x4 s; } o;
        o.u[0] = pkbf(v[0], v[1]);
        o.u[1] = pkbf(v[2], v[3]);
        *(s16x4*)(attb + m * LDS_K + k) = o.s;   // 8 B, aligned (k % 4 == 0)
    }
    __syncthreads();

    // Clamp the single OOB row (n==31999); its table rows are never gathered.
    const int n_base = blockIdx.x * 64 + wave * 16;
    const int n = n_base + mrow;
    const int nc = n < INNER ? n : (INNER - 1);
    const float* wp = W + (size_t)nc * K_DIM;

    f32x4 acc[4];
    #pragma unroll
    for (int j = 0; j < 4; j++) acc[j] = (f32x4){0.f, 0.f, 0.f, 0.f};

    // 2-stage x 4-iteration pipeline; streaming (nt) W loads.
    f32x4 bufA[8], bufB[8];

#define LOADCH(buf, c)                                                   \
    _Pragma("unroll")                                                    \
    for (int i = 0; i < 4; i++) {                                        \
        buf[2*i]   = __builtin_nontemporal_load(                         \
            (const f32x4*)(wp + (c)*128 + i*32 + q8));                   \
        buf[2*i+1] = __builtin_nontemporal_load(                         \
            (const f32x4*)(wp + (c)*128 + i*32 + q8 + 4));               \
    }

#define COMPCH(buf, c)                                                   \
    _Pragma("unroll")                                                    \
    for (int i = 0; i < 4; i++) {                                        \
        const bf16x8 a = cvt8(buf[2*i], buf[2*i+1]);                     \
        const int koff = (c)*128 + i*32 + q8;                            \
        _Pragma("unroll")                                                \
        for (int j = 0; j < 4; j++) {                                    \
            const bf16x8 b = *(const bf16x8*)(                           \
                attb + (j * 16 + mrow) * LDS_K + koff);                  \
            acc[j] = __builtin_amdgcn_mfma_f32_16x16x32_bf16(            \
                a, b, acc[j], 0, 0, 0);                                  \
        }                                                                \
    }

    LOADCH(bufA, 0)
    LOADCH(bufB, 1)
    COMPCH(bufA, 0)
    LOADCH(bufA, 2)
    COMPCH(bufB, 1)
    LOADCH(bufB, 3)
    COMPCH(bufA, 2)
    COMPCH(bufB, 3)

#undef LOADCH
#undef COMPCH

    // D layout: col(lane&15) = m-within-16, row(quad*4+reg) = W-row offset.
    // Lp/Lm stores are NORMAL (cached): kernel 2 gathers them with ~9x reuse.
    #pragma unroll
    for (int j = 0; j < 4; j++) {
        const int m = j * 16 + mrow;
        #pragma unroll
        for (int r = 0; r < 4; r++) {
            const float x = acc[j][r];
            const float e = __expf(-fabsf(x));       // e^{-|x|} in (0,1]
            const float L = __logf(1.0f + e);        // log1p, arg in (1,2]
            float lsp = fminf(x, 0.f) - L;           // logsig(x)  <= 0
            float lsm = lsp - x;                     // logsig(-x) (exact identity)
            lsp = fmaxf(lsp, LOG_EPS);               // reference eps clip
            lsm = fmaxf(lsm, LOG_EPS);
            const size_t row = (size_t)(n_base + quad * 4 + r) * M_DIM;
            Lp[row + m] = (_Float16)lsp;
            Lm[row + m] = (_Float16)lsm;
        }
    }
}

// Kernel 2: out[m][v] = sum_d Ltab[sign_d][idx_d][m] — pure gather-accumulate.
// R10 change: path_index/path_sign loads and out stores are NON-TEMPORAL
// (read/written exactly once device-wide) so they don't evict the Lp/Lm
// table rows, which have ~9x average reuse and are the kernel's hot set.
// The i-loop is unrolled 2x: 36 independent gathers in flight per wave.
__global__ __launch_bounds__(256) void hsoftmax_kernel(
    const char*  __restrict__ tab,         // Lp base; Lm at +LM_BYTE_OFF
    const int*   __restrict__ path_index,  // [VOCAB*DEPTH]
    const float* __restrict__ path_sign,   // [VOCAB*DEPTH]
    float* __restrict__ out)               // [64][32000]
{
    __shared__ unsigned int packed[32 * DEPTH];   // byte offset incl. table select
    __shared__ float2 res2[32][33];               // [v][m/2], 264B rows

    const int tid = threadIdx.x;
    const int wave = tid >> 6;
    const int lane = tid & 63;
    const int half = lane >> 5;                   // which v of the pair
    const int sub  = lane & 31;                   // m = 2*sub, 2*sub+1
    const int v_base = blockIdx.x * 32;
    const int base = v_base * DEPTH;

    for (int t = tid; t < 32 * DEPTH; t += 256) {
        const unsigned int idx =
            (unsigned int)__builtin_nontemporal_load(path_index + base + t);
        const float s = __builtin_nontemporal_load(path_sign + base + t);
        packed[t] = (idx << 7) + (s < 0.f ? LM_BYTE_OFF : 0u);
    }
    __syncthreads();

    const int boff = sub * 4;                     // this lane's m-pair bytes
    #pragma unroll 2
    for (int i = 0; i < 4; i++) {
        const int vloc = wave * 8 + 2 * i + half;
        float a0 = 0.f, a1 = 0.f;
        #pragma unroll
        for (int d = 0; d < DEPTH; d++) {
            const unsigned int off = packed[vloc * DEPTH + d];
            const unsigned int xx = *(const unsigned int*)(tab + off + boff);
            union { unsigned int u; f16x2 h; } cv; cv.u = xx;
            a0 += (float)cv.h[0];
            a1 += (float)cv.h[1];
        }
        res2[vloc][sub] = make_float2(a0, a1);
    }
    __syncthreads();

    // Coalesced streaming stores: 256 thr x 8 iters cover 64 m x 32 v.
    #pragma unroll
    for (int it = 0; it < 8; it++) {
        const int m = it * 8 + (tid >> 5);
        const int vloc = tid & 31;
        __builtin_nontemporal_store(
            ((const float*)&res2[vloc][0])[m],
            out + (size_t)m * VOCAB + v_base + vloc);
    }
}

extern "C" void kernel_launch(void* const* d_in, const int* in_sizes, int n_in,
                              void* d_out, int out_size, void* d_ws, size_t ws_size,
                              hipStream_t stream) {
    const float* att        = (const float*)d_in[0];
    const float* W          = (const float*)d_in[1];
    const int*   path_index = (const int*)d_in[2];
    const float* path_sign  = (const float*)d_in[3];
    // d_in[4] = path_bias: algebraically redundant ((1-sign)/2), unused.

    _Float16* Lp = (_Float16*)d_ws;                            // 4.096 MB
    _Float16* Lm = (_Float16*)((char*)d_ws + LM_BYTE_OFF);     // 4.096 MB
    float* out = (float*)d_out;

    gemm_ls_kernel<<<500, 256, 0, stream>>>(W, att, Lp, Lm);
    hsoftmax_kernel<<<1000, 256, 0, stream>>>((const char*)Lp, path_index, path_sign, out);
}

// Round 4
// 115.738 us; speedup vs baseline: 1.0695x; 1.0695x over previous
//
#include <hip/hip_runtime.h>
#include <hip/hip_bf16.h>

#define INNER 31999
#define VOCAB 32000
#define DEPTH 18
#define M_DIM 64      // B*T = 4*16
#define K_DIM 512     // D
#define LDS_K (K_DIM + 8)   // +8 bf16 pad -> 2-way-max (free) ds_read_b128

// Byte offset of the Lm table relative to Lp within the workspace.
#define LM_BYTE_OFF 4194304u
#define LOG_EPS -20.723265f   // log(1e-9): reference's per-depth clip floor

typedef __attribute__((ext_vector_type(8))) short bf16x8;
typedef __attribute__((ext_vector_type(4))) short s16x4;
typedef __attribute__((ext_vector_type(4))) float f32x4;
typedef __attribute__((ext_vector_type(2))) _Float16 f16x2;

// Pack two fp32 -> bf16x2 in one dword (round-half-up + v_perm).
__device__ __forceinline__ unsigned int pkbf(float a, float b) {
    const unsigned int ua = __float_as_uint(a) + 0x8000u;
    const unsigned int ub = __float_as_uint(b) + 0x8000u;
    return __builtin_amdgcn_perm(ub, ua, 0x07060302u);  // [a.hi16 | b.hi16]
}

__device__ __forceinline__ bf16x8 cvt8(f32x4 lo, f32x4 hi) {
    union { unsigned int u[4]; bf16x8 v; } r;
    r.u[0] = pkbf(lo[0], lo[1]);
    r.u[1] = pkbf(lo[2], lo[3]);
    r.u[2] = pkbf(hi[0], hi[1]);
    r.u[3] = pkbf(hi[2], hi[3]);
    return r.v;
}

// Kernel 1: x[n][m] = sum_k W[n][k]*att[m][k] (bf16 MFMA, fp32 accum), then
// epilogue computes both log-sigmoids once per (n,m) and stores f16 tables
// Lp/Lm (18x fewer transcendental evals than doing it in kernel 2).
// History: R9 explicit 2-deep register pipeline = null (compiler already
// schedules loads under full unroll; kept, harmless). R10 non-temporal
// hints on W/out = REGRESSED +7us (nt policy demotes the stream path on
// gfx950) — reverted; plain cached loads/stores below.
__global__ __launch_bounds__(256) void gemm_ls_kernel(
    const float* __restrict__ W,     // [31999][512] fp32
    const float* __restrict__ att,   // [64][512] fp32
    _Float16* __restrict__ Lp,       // [32000][64] f16: logsig(+x)
    _Float16* __restrict__ Lm)       // [32000][64] f16: logsig(-x)
{
    __shared__ __align__(16) unsigned short attb[M_DIM * LDS_K];  // 65 KB bf16

    const int tid  = threadIdx.x;
    const int wave = tid >> 6;
    const int lane = tid & 63;
    const int mrow = lane & 15;
    const int quad = lane >> 4;
    const int q8   = quad * 8;

    // Stage att (128 KB fp32, L2-resident) -> LDS bf16, coalesced, once.
    #pragma unroll
    for (int i = 0; i < 32; i++) {
        const int f4 = i * 256 + tid;            // float4 index, 0..8191
        const f32x4 v = ((const f32x4*)att)[f4];
        const int f = f4 * 4;
        const int m = f >> 9, k = f & (K_DIM - 1);
        union { unsigned int u[2]; s16x4 s; } o;
        o.u[0] = pkbf(v[0], v[1]);
        o.u[1] = pkbf(v[2], v[3]);
        *(s16x4*)(attb + m * LDS_K + k) = o.s;   // 8 B, aligned (k % 4 == 0)
    }
    __syncthreads();

    // Clamp the single OOB row (n==31999); its table rows are never gathered.
    const int n_base = blockIdx.x * 64 + wave * 16;
    const int n = n_base + mrow;
    const int nc = n < INNER ? n : (INNER - 1);
    const float* wp = W + (size_t)nc * K_DIM;

    f32x4 acc[4];
    #pragma unroll
    for (int j = 0; j < 4; j++) acc[j] = (f32x4){0.f, 0.f, 0.f, 0.f};

    // 2-stage x 4-iteration pipeline. Each chunk c covers k = c*128+q8 ..,
    // 4 k-iterations (8 dwordx4 loads) per buffer. All indices compile-time
    // constant -> registers.
    f32x4 bufA[8], bufB[8];

#define LOADCH(buf, c)                                                   \
    _Pragma("unroll")                                                    \
    for (int i = 0; i < 4; i++) {                                        \
        buf[2*i]   = *(const f32x4*)(wp + (c)*128 + i*32 + q8);          \
        buf[2*i+1] = *(const f32x4*)(wp + (c)*128 + i*32 + q8 + 4);      \
    }

#define COMPCH(buf, c)                                                   \
    _Pragma("unroll")                                                    \
    for (int i = 0; i < 4; i++) {                                        \
        const bf16x8 a = cvt8(buf[2*i], buf[2*i+1]);                     \
        const int koff = (c)*128 + i*32 + q8;                            \
        _Pragma("unroll")                                                \
        for (int j = 0; j < 4; j++) {                                    \
            const bf16x8 b = *(const bf16x8*)(                           \
                attb + (j * 16 + mrow) * LDS_K + koff);                  \
            acc[j] = __builtin_amdgcn_mfma_f32_16x16x32_bf16(            \
                a, b, acc[j], 0, 0, 0);                                  \
        }                                                                \
    }

    LOADCH(bufA, 0)
    LOADCH(bufB, 1)
    COMPCH(bufA, 0)
    LOADCH(bufA, 2)
    COMPCH(bufB, 1)
    LOADCH(bufB, 3)
    COMPCH(bufA, 2)
    COMPCH(bufB, 3)

#undef LOADCH
#undef COMPCH

    // D layout: col(lane&15) = m-within-16, row(quad*4+reg) = W-row offset.
    #pragma unroll
    for (int j = 0; j < 4; j++) {
        const int m = j * 16 + mrow;
        #pragma unroll
        for (int r = 0; r < 4; r++) {
            const float x = acc[j][r];
            const float e = __expf(-fabsf(x));       // e^{-|x|} in (0,1]
            const float L = __logf(1.0f + e);        // log1p, arg in (1,2]
            float lsp = fminf(x, 0.f) - L;           // logsig(x)  <= 0
            float lsm = lsp - x;                     // logsig(-x) (exact identity)
            lsp = fmaxf(lsp, LOG_EPS);               // reference eps clip
            lsm = fmaxf(lsm, LOG_EPS);
            const size_t row = (size_t)(n_base + quad * 4 + r) * M_DIM;
            Lp[row + m] = (_Float16)lsp;
            Lm[row + m] = (_Float16)lsm;
        }
    }
}

// Kernel 2: out[m][v] = sum_d Ltab[sign_d][idx_d][m] — pure gather-accumulate.
// packed[] holds a ready-to-use byte offset: idx*128 + (sign<0 ? LM_OFF : 0).
// Per-depth body: LDS dword (2-way broadcast), one coalesced dword gather
// (32 lanes x 4 B = one full 128 B row), 2 cvt, 2 add. R10 nt hints on
// path/out = part of the +7us regression — reverted to plain accesses.
__global__ __launch_bounds__(256) void hsoftmax_kernel(
    const char*  __restrict__ tab,         // Lp base; Lm at +LM_BYTE_OFF
    const int*   __restrict__ path_index,  // [VOCAB*DEPTH]
    const float* __restrict__ path_sign,   // [VOCAB*DEPTH]
    float* __restrict__ out)               // [64][32000]
{
    __shared__ unsigned int packed[32 * DEPTH];   // byte offset incl. table select
    __shared__ float2 res2[32][33];               // [v][m/2], 264B rows

    const int tid = threadIdx.x;
    const int wave = tid >> 6;
    const int lane = tid & 63;
    const int half = lane >> 5;                   // which v of the pair
    const int sub  = lane & 31;                   // m = 2*sub, 2*sub+1
    const int v_base = blockIdx.x * 32;
    const int base = v_base * DEPTH;

    for (int t = tid; t < 32 * DEPTH; t += 256) {
        const unsigned int idx = (unsigned int)path_index[base + t];
        const float s = path_sign[base + t];
        packed[t] = (idx << 7) + (s < 0.f ? LM_BYTE_OFF : 0u);
    }
    __syncthreads();

    const int boff = sub * 4;                     // this lane's m-pair bytes
    for (int i = 0; i < 4; i++) {
        const int vloc = wave * 8 + 2 * i + half;
        float a0 = 0.f, a1 = 0.f;
        #pragma unroll
        for (int d = 0; d < DEPTH; d++) {
            const unsigned int off = packed[vloc * DEPTH + d];
            const unsigned int xx = *(const unsigned int*)(tab + off + boff);
            union { unsigned int u; f16x2 h; } cv; cv.u = xx;
            a0 += (float)cv.h[0];
            a1 += (float)cv.h[1];
        }
        res2[vloc][sub] = make_float2(a0, a1);
    }
    __syncthreads();

    // Coalesced stores: 256 thr x 8 iters cover 64 m x 32 v.
    #pragma unroll
    for (int it = 0; it < 8; it++) {
        const int m = it * 8 + (tid >> 5);
        const int vloc = tid & 31;
        out[(size_t)m * VOCAB + v_base + vloc] = ((const float*)&res2[vloc][0])[m];
    }
}

extern "C" void kernel_launch(void* const* d_in, const int* in_sizes, int n_in,
                              void* d_out, int out_size, void* d_ws, size_t ws_size,
                              hipStream_t stream) {
    const float* att        = (const float*)d_in[0];
    const float* W          = (const float*)d_in[1];
    const int*   path_index = (const int*)d_in[2];
    const float* path_sign  = (const float*)d_in[3];
    // d_in[4] = path_bias: algebraically redundant ((1-sign)/2), unused.

    _Float16* Lp = (_Float16*)d_ws;                            // 4.096 MB
    _Float16* Lm = (_Float16*)((char*)d_ws + LM_BYTE_OFF);     // 4.096 MB
    float* out = (float*)d_out;

    gemm_ls_kernel<<<500, 256, 0, stream>>>(W, att, Lp, Lm);
    hsoftmax_kernel<<<1000, 256, 0, stream>>>((const char*)Lp, path_index, path_sign, out);
}